// Round 12
// baseline (450.279 us; speedup 1.0000x reference)
//
#include <hip/hip_runtime.h>

// LSTM (B=8192, T=168, F=64, H=50) + MLP head, fused, f16 MFMA + fp32 state.
// Round 12: round-11 barrier-free single-wave structure with CORRECTED
// ds_read_b64_tr_b16 addressing: per-lane addr = base + kg*256 + cc*8
// (16-lane group window = 128 B, lane slot = (l&15)*8 B; r11 wrongly used a
// group-uniform address -> all lanes read the same value per m156 semantics).
// One wave owns 16 batch rows end-to-end: 64 MFMA/step, in-lane gates,
// C->A transpose of h via private LDS (4x ds_write_b64 + 4x tr-read).
// Zero s_barrier in the loop. 512 blocks x 64 threads.

#define B_N 8192
#define T_N 168
#define F_N 64
#define H_N 50
#define HEAD_N 100
#define RS (T_N * F_N)  // 10752

typedef _Float16 f16x8 __attribute__((ext_vector_type(8)));
typedef _Float16 f16x4 __attribute__((ext_vector_type(4)));
typedef float    f32x4 __attribute__((ext_vector_type(4)));

#define LOG2E  1.4426950408889634f
#define LOG2E2 2.8853900817779268f
#define MFMA __builtin_amdgcn_mfma_f32_16x16x32_f16

__device__ __forceinline__ float rcp_f(float v) { return __builtin_amdgcn_rcpf(v); }
#if __has_builtin(__builtin_amdgcn_exp2f)
__device__ __forceinline__ float exp2_f(float v) { return __builtin_amdgcn_exp2f(v); }
#else
__device__ __forceinline__ float exp2_f(float v) { return __expf(0.6931471805599453f * v); }
#endif

__device__ __forceinline__ f16x8 cvt8(f32x4 a, f32x4 b) {
    f16x8 r;
    #pragma unroll
    for (int j = 0; j < 4; ++j) { r[j] = (_Float16)a[j]; r[4 + j] = (_Float16)b[j]; }
    return r;
}

__launch_bounds__(64, 1)
__global__ void lstm_fused(const float* __restrict__ x,
                           const float* __restrict__ Wx,
                           const float* __restrict__ Wh,
                           const float* __restrict__ b,
                           const float* __restrict__ W1,
                           const float* __restrict__ b1,
                           const float* __restrict__ W2,
                           const float* __restrict__ b2,
                           float* __restrict__ out)
{
    // h transpose buffer, [unit][row] f16, double-buffered. 4 KB, 128B-aligned
    // (tr-read windows are 128 B).
    __shared__ alignas(128) _Float16 h_lds[2][64][16];

    const int lane = threadIdx.x;      // 0..63 (single wave)
    const int cc   = lane & 15;        // tile col / batch row / tr lane slot
    const int kg   = lane >> 4;        // k-group
    const int r0   = kg * 4;           // C-frag row base
    const int R0   = blockIdx.x * 16;  // batch rows of this wave

    // ---- all 16 col-tiles' weights, VGPR-resident, exp2-prescaled ---------
    // col = ct*16 + cc ; gate g = ct>>2 ; unit u = (ct&3)*16 + cc
    f16x8 wxf[16][2], whf[16][2];
    float bg[16];
    #pragma unroll
    for (int ct = 0; ct < 16; ++ct) {
        const int g = ct >> 2;
        const int u = (ct & 3) * 16 + cc;
        const float sc = (g == 2) ? LOG2E2 : LOG2E;   // g-gate: fold tanh's 2x
        const bool uv = (u < H_N);
        bg[ct] = uv ? b[g * H_N + u] * sc : 0.0f;
        #pragma unroll
        for (int ks = 0; ks < 2; ++ks) {
            f16x8 vx, vh;
            #pragma unroll
            for (int i = 0; i < 8; ++i) {
                int k = ks * 32 + kg * 8 + i;   // same k-map as A-frags
                vx[i] = (_Float16)(uv ? Wx[k * 200 + g * H_N + u] * sc : 0.0f);
                vh[i] = (_Float16)((uv && k < H_N) ? Wh[k * 200 + g * H_N + u] * sc : 0.0f);
            }
            wxf[ct][ks] = vx;
            whf[ct][ks] = vh;
        }
    }

    // zero h(0) buffer
    #pragma unroll
    for (int i = 0; i < 4; ++i)
        reinterpret_cast<f16x4*>(&h_lds[0][0][0])[lane + i * 64] = (f16x4){0, 0, 0, 0};

    // x A-frag loads: lane reads row R0+cc, k-cols kg*8..+8 (+32 for ks=1)
    const float* xb = x + (size_t)(R0 + cc) * RS + kg * 8;
    f32x4 xp0, xp1, xp2, xp3;          // x(t+1) in flight
    f32x4 zacc[16];                    // z accumulators (16 tiles x 4 rows)
    float cst[16];                     // cell state
    #pragma unroll
    for (int i = 0; i < 16; ++i) cst[i] = 0.0f;

    {   // prologue: zacc = bias + x(0)@Wx ; xp = x(1)
        f32x4 t0 = *(const f32x4*)(xb + 0);
        f32x4 t1 = *(const f32x4*)(xb + 4);
        f32x4 t2 = *(const f32x4*)(xb + 32);
        f32x4 t3 = *(const f32x4*)(xb + 36);
        xp0 = *(const f32x4*)(xb + F_N + 0);
        xp1 = *(const f32x4*)(xb + F_N + 4);
        xp2 = *(const f32x4*)(xb + F_N + 32);
        xp3 = *(const f32x4*)(xb + F_N + 36);
        f16x8 xa0 = cvt8(t0, t1), xa1 = cvt8(t2, t3);
        #pragma unroll
        for (int ct = 0; ct < 16; ++ct) {
            f32x4 a = {bg[ct], bg[ct], bg[ct], bg[ct]};
            a = MFMA(xa0, wxf[ct][0], a, 0, 0, 0);
            zacc[ct] = MFMA(xa1, wxf[ct][1], a, 0, 0, 0);
        }
    }
    const float* xld = xb + 2 * F_N;   // next load: x(2)

    // tr-read base: window = base + kg*256 (units kg*8..+3 for offset 0),
    // lane slot = cc*8 bytes; buffers 2048 B apart.
    const uint32_t trbase0 =
        (uint32_t)(uintptr_t)(&h_lds[0][0][0]) + (kg << 8) + (cc << 3);
    const uint32_t trbase1 = trbase0 + 2048;

    // gates: merged-rcp pairs, exp2 domain (weights prescaled; g by 2x)
#define GATEC(q, i)                                                            \
    {                                                                          \
        float A_ = exp2_f(-zi[i]);                                             \
        float Bv = exp2_f(-zg[i]);                                             \
        float Fv = exp2_f(-zf[i]);                                             \
        float sf_ = rcp_f(1.0f + Fv);                                          \
        float r1_ = rcp_f((1.0f + A_) * (1.0f + Bv));                          \
        float cn_ = fmaf(sf_, cst[(q) * 4 + (i)], (1.0f - Bv) * r1_);          \
        cst[(q) * 4 + (i)] = cn_;                                              \
        float Cv = exp2_f(-zo[i]);                                             \
        float eD_ = fminf(-LOG2E2 * cn_, 80.0f);                               \
        float Dv = exp2_f(eD_);                                                \
        float r2_ = rcp_f((1.0f + Cv) * (1.0f + Dv));                          \
        ph[i] = (_Float16)((1.0f - Dv) * r2_);                                 \
    }

    // One step t (P=t&1): tr-read h(t) from h_lds[P]; z += h@Wh; gates;
    // write h(t+1) -> h_lds[P^1]; reinit zacc = bias + x(t+1)@Wx; load x(t+2).
    // NO barrier: all ordering is same-wave lgkmcnt + in-order DS pipe.
#define STEP(P, DO_LOAD, DO_XNEXT)                                             \
    {                                                                          \
        f16x4 t0, t1, t2, t3;                                                  \
        asm volatile("s_waitcnt lgkmcnt(0)" ::: "memory");                     \
        asm volatile("ds_read_b64_tr_b16 %0, %1"                               \
                     : "=v"(t0) : "v"(trbase##P) : "memory");                  \
        asm volatile("ds_read_b64_tr_b16 %0, %1 offset:128"                    \
                     : "=v"(t1) : "v"(trbase##P) : "memory");                  \
        asm volatile("ds_read_b64_tr_b16 %0, %1 offset:1024"                   \
                     : "=v"(t2) : "v"(trbase##P) : "memory");                  \
        asm volatile("ds_read_b64_tr_b16 %0, %1 offset:1152"                   \
                     : "=v"(t3) : "v"(trbase##P) : "memory");                  \
        asm volatile("s_waitcnt lgkmcnt(0)" ::: "memory");                     \
        __builtin_amdgcn_sched_barrier(0);                                     \
        f16x8 ha0 = __builtin_shufflevector(t0, t1, 0, 1, 2, 3, 4, 5, 6, 7);   \
        f16x8 ha1 = __builtin_shufflevector(t2, t3, 0, 1, 2, 3, 4, 5, 6, 7);   \
        _Pragma("unroll")                                                      \
        for (int ct = 0; ct < 16; ++ct) {                                      \
            zacc[ct] = MFMA(ha0, whf[ct][0], zacc[ct], 0, 0, 0);               \
            zacc[ct] = MFMA(ha1, whf[ct][1], zacc[ct], 0, 0, 0);               \
        }                                                                      \
        f16x8 xa0, xa1;                                                        \
        if (DO_XNEXT) { xa0 = cvt8(xp0, xp1); xa1 = cvt8(xp2, xp3); }          \
        _Pragma("unroll")                                                      \
        for (int q = 0; q < 4; ++q) {                                          \
            f32x4 zi = zacc[q], zf = zacc[4 + q], zg = zacc[8 + q], zo = zacc[12 + q]; \
            f16x4 ph;                                                          \
            GATEC(q, 0) GATEC(q, 1) GATEC(q, 2) GATEC(q, 3)                    \
            *reinterpret_cast<f16x4*>(&h_lds[P ^ 1][q * 16 + cc][r0]) = ph;    \
            if (DO_XNEXT) {                                                    \
                _Pragma("unroll")                                              \
                for (int gg = 0; gg < 4; ++gg) {                               \
                    const int c2 = gg * 4 + q;                                 \
                    f32x4 a = {bg[c2], bg[c2], bg[c2], bg[c2]};                \
                    a = MFMA(xa0, wxf[c2][0], a, 0, 0, 0);                     \
                    zacc[c2] = MFMA(xa1, wxf[c2][1], a, 0, 0, 0);              \
                }                                                              \
            }                                                                  \
        }                                                                      \
        if (DO_LOAD) {                                                         \
            xp0 = *(const f32x4*)(xld + 0);                                    \
            xp1 = *(const f32x4*)(xld + 4);                                    \
            xp2 = *(const f32x4*)(xld + 32);                                   \
            xp3 = *(const f32x4*)(xld + 36);                                   \
            xld += F_N;                                                        \
        }                                                                      \
    }

    for (int it = 0; it < 83; ++it) {   // t = 0..165
        STEP(0, 1, 1)
        STEP(1, 1, 1)
    }
    STEP(0, 0, 1)   // t=166: no x(168) load
    STEP(1, 0, 0)   // t=167: final h(168) -> h_lds[0]
#undef STEP
#undef GATEC

    // ---- MLP head: relu(h@W1 + b1)@W2 + b2 + x[:, -1, 0] ------------------
    // h(168) in h_lds[0], [unit][row]; lane handles batch row cc, units kg+4k.
    asm volatile("s_waitcnt lgkmcnt(0)" ::: "memory");
    float hrow[H_N];
    #pragma unroll
    for (int hk = 0; hk < H_N; ++hk) hrow[hk] = (float)h_lds[0][hk][cc];
    float sacc = 0.0f;
    for (int u = kg; u < HEAD_N; u += 4) {
        float s = b1[u];
        #pragma unroll
        for (int hk = 0; hk < H_N; ++hk)
            s = fmaf(hrow[hk], W1[hk * HEAD_N + u], s);
        sacc = fmaf(fmaxf(s, 0.0f), W2[u], sacc);
    }
    sacc += __shfl_xor(sacc, 16);
    sacc += __shfl_xor(sacc, 32);
    if (kg == 0)
        out[R0 + cc] = sacc + b2[0] + x[(size_t)(R0 + cc) * RS + (T_N - 1) * F_N];
}

extern "C" void kernel_launch(void* const* d_in, const int* in_sizes, int n_in,
                              void* d_out, int out_size, void* d_ws, size_t ws_size,
                              hipStream_t stream) {
    const float* x  = (const float*)d_in[0];
    const float* Wx = (const float*)d_in[1];
    const float* Wh = (const float*)d_in[2];
    const float* b  = (const float*)d_in[3];
    const float* W1 = (const float*)d_in[4];
    const float* b1 = (const float*)d_in[5];
    const float* W2 = (const float*)d_in[6];
    const float* b2 = (const float*)d_in[7];
    float* out = (float*)d_out;

    lstm_fused<<<dim3(B_N / 16), dim3(64), 0, stream>>>(x, Wx, Wh, b, W1, b1, W2, b2, out);
}

// Round 13
// 267.473 us; speedup vs baseline: 1.6835x; 1.6835x over previous
//
#include <hip/hip_runtime.h>

// LSTM (B=8192, T=168, F=64, H=50) + MLP head, fused, f16 MFMA + fp32 state.
// Round 13: 2-wave blocks. Each 128-thr block owns one 16-row chain; wave W
// owns units [W*32, W*32+32) = 8 col-tiles -> 128 weight VGPRs (r12's 256-reg
// spill fixed). Per step: 4x ds_read_b64_tr_b16 (r12-validated addressing,
// all 64 units), 16 h-MFMA + 16 x-MFMA, merged-rcp exp2 gates (8 cells/lane),
// 2x b64 h-writes, ONE 2-wave lgkm barrier. x loaded global->reg in A-frag
// layout. 512 blocks, 4 waves/CU, 1 wave/SIMD.

#define B_N 8192
#define T_N 168
#define F_N 64
#define H_N 50
#define HEAD_N 100
#define RS (T_N * F_N)  // 10752

typedef _Float16 f16x8 __attribute__((ext_vector_type(8)));
typedef _Float16 f16x4 __attribute__((ext_vector_type(4)));
typedef float    f32x4 __attribute__((ext_vector_type(4)));

#define LOG2E  1.4426950408889634f
#define LOG2E2 2.8853900817779268f
#define MFMA __builtin_amdgcn_mfma_f32_16x16x32_f16

// LDS barrier: drain own LDS ops, barrier, compiler fence both sides.
#define BAR()                                                        \
    do {                                                             \
        asm volatile("s_waitcnt lgkmcnt(0)" ::: "memory");           \
        __builtin_amdgcn_s_barrier();                                \
        asm volatile("" ::: "memory");                               \
    } while (0)

__device__ __forceinline__ float rcp_f(float v) { return __builtin_amdgcn_rcpf(v); }
#if __has_builtin(__builtin_amdgcn_exp2f)
__device__ __forceinline__ float exp2_f(float v) { return __builtin_amdgcn_exp2f(v); }
#else
__device__ __forceinline__ float exp2_f(float v) { return __expf(0.6931471805599453f * v); }
#endif

__device__ __forceinline__ f16x8 cvt8(f32x4 a, f32x4 b) {
    f16x8 r;
    #pragma unroll
    for (int j = 0; j < 4; ++j) { r[j] = (_Float16)a[j]; r[4 + j] = (_Float16)b[j]; }
    return r;
}

__launch_bounds__(128, 1)
__global__ void lstm_fused(const float* __restrict__ x,
                           const float* __restrict__ Wx,
                           const float* __restrict__ Wh,
                           const float* __restrict__ b,
                           const float* __restrict__ W1,
                           const float* __restrict__ b1,
                           const float* __restrict__ W2,
                           const float* __restrict__ b2,
                           float* __restrict__ out)
{
    // h buffer [unit][row] f16, double-buffered, 128B-aligned (tr windows).
    __shared__ alignas(128) _Float16 h_lds[2][64][16];
    __shared__ float hrelu[16][HEAD_N];

    const int tid  = threadIdx.x;      // 0..127
    const int lane = tid & 63;
    const int W    = tid >> 6;         // wave id 0,1: units W*32..+32
    const int cc   = lane & 15;        // batch row / tile col
    const int kg   = lane >> 4;        // k-group
    const int R0   = blockIdx.x * 16;  // batch rows of this block

    // ---- this wave's 8 col-tiles of weights, VGPR-resident, prescaled -----
    // tile (g,q): gate g, units u = W*32 + q*16 + cc
    f16x8 wxf[4][2][2], whf[4][2][2];
    float bgv[4][2];
    #pragma unroll
    for (int g = 0; g < 4; ++g) {
        const float sc = (g == 2) ? LOG2E2 : LOG2E;   // g-gate: fold tanh's 2x
        #pragma unroll
        for (int q = 0; q < 2; ++q) {
            const int u = W * 32 + q * 16 + cc;
            const bool uv = (u < H_N);
            bgv[g][q] = uv ? b[g * H_N + u] * sc : 0.0f;
            #pragma unroll
            for (int ks = 0; ks < 2; ++ks) {
                f16x8 vx, vh;
                #pragma unroll
                for (int i = 0; i < 8; ++i) {
                    int k = ks * 32 + kg * 8 + i;   // same k-map as A-frags
                    vx[i] = (_Float16)(uv ? Wx[k * 200 + g * H_N + u] * sc : 0.0f);
                    vh[i] = (_Float16)((uv && k < H_N) ? Wh[k * 200 + g * H_N + u] * sc : 0.0f);
                }
                wxf[g][q][ks] = vx;
                whf[g][q][ks] = vh;
            }
        }
    }

    // zero h(0) buffer 0
    #pragma unroll
    for (int i = 0; i < 4; ++i)
        reinterpret_cast<f16x4*>(&h_lds[0][0][0])[tid + i * 128] = (f16x4){0, 0, 0, 0};

    // x A-frag loads: lane reads row R0+cc, k-cols kg*8 + {0..7, 32..39}
    const float* xb = x + (size_t)(R0 + cc) * RS + kg * 8;
    f32x4 xp0, xp1, xp2, xp3;          // x(t+1) in flight
    f32x4 zacc[4][2];                  // z accumulators [gate][q]
    float cst[8];                      // cell state [q*4+i]
    #pragma unroll
    for (int i = 0; i < 8; ++i) cst[i] = 0.0f;

    {   // prologue: zacc = bias + x(0)@Wx ; xp = x(1)
        f32x4 t0 = *(const f32x4*)(xb + 0);
        f32x4 t1 = *(const f32x4*)(xb + 4);
        f32x4 t2 = *(const f32x4*)(xb + 32);
        f32x4 t3 = *(const f32x4*)(xb + 36);
        xp0 = *(const f32x4*)(xb + F_N + 0);
        xp1 = *(const f32x4*)(xb + F_N + 4);
        xp2 = *(const f32x4*)(xb + F_N + 32);
        xp3 = *(const f32x4*)(xb + F_N + 36);
        f16x8 xa0 = cvt8(t0, t1), xa1 = cvt8(t2, t3);
        #pragma unroll
        for (int g = 0; g < 4; ++g)
            #pragma unroll
            for (int q = 0; q < 2; ++q) {
                f32x4 a = {bgv[g][q], bgv[g][q], bgv[g][q], bgv[g][q]};
                a = MFMA(xa0, wxf[g][q][0], a, 0, 0, 0);
                zacc[g][q] = MFMA(xa1, wxf[g][q][1], a, 0, 0, 0);
            }
    }
    const float* xld = xb + 2 * F_N;   // next load: x(2)
    __syncthreads();                   // h(0) + (nothing else) visible

    // tr-read base (r12-validated): window = base + kg*256, lane slot cc*8.
    // offsets {0,128,1024,1152} -> units {kg*8..+3, +4..+7, 32+kg*8..+3, ..+7}
    const uint32_t trbase0 =
        (uint32_t)(uintptr_t)(&h_lds[0][0][0]) + (kg << 8) + (cc << 3);
    const uint32_t trbase1 = trbase0 + 2048;

    // gates: merged-rcp pairs, exp2 domain (weights prescaled; g by 2x)
#define GATEC(q, i)                                                            \
    {                                                                          \
        float A_ = exp2_f(-zi[i]);                                             \
        float Bv = exp2_f(-zg[i]);                                             \
        float Fv = exp2_f(-zf[i]);                                             \
        float sf_ = rcp_f(1.0f + Fv);                                          \
        float r1_ = rcp_f((1.0f + A_) * (1.0f + Bv));                          \
        float cn_ = fmaf(sf_, cst[(q) * 4 + (i)], (1.0f - Bv) * r1_);          \
        cst[(q) * 4 + (i)] = cn_;                                              \
        float Cv = exp2_f(-zo[i]);                                             \
        float eD_ = fminf(-LOG2E2 * cn_, 80.0f);                               \
        float Dv = exp2_f(eD_);                                                \
        float r2_ = rcp_f((1.0f + Cv) * (1.0f + Dv));                          \
        ph[i] = (_Float16)((1.0f - Dv) * r2_);                                 \
    }

    // Step t (P=t&1): tr-read h(t) from h_lds[P] (xa cvt in latency shadow);
    // z += h@Wh; gates -> h(t+1) into h_lds[P^1][this wave's units]; zacc
    // reinit = bias + x(t+1)@Wx; load x(t+2); ONE 2-wave barrier.
#define STEP(P, DO_LOAD, DO_XNEXT)                                             \
    {                                                                          \
        f16x4 t0, t1, t2, t3;                                                  \
        asm volatile("ds_read_b64_tr_b16 %0, %1"                               \
                     : "=v"(t0) : "v"(trbase##P) : "memory");                  \
        asm volatile("ds_read_b64_tr_b16 %0, %1 offset:128"                    \
                     : "=v"(t1) : "v"(trbase##P) : "memory");                  \
        asm volatile("ds_read_b64_tr_b16 %0, %1 offset:1024"                   \
                     : "=v"(t2) : "v"(trbase##P) : "memory");                  \
        asm volatile("ds_read_b64_tr_b16 %0, %1 offset:1152"                   \
                     : "=v"(t3) : "v"(trbase##P) : "memory");                  \
        f16x8 xa0, xa1;                                                        \
        if (DO_XNEXT) { xa0 = cvt8(xp0, xp1); xa1 = cvt8(xp2, xp3); }          \
        asm volatile("s_waitcnt lgkmcnt(0)" ::: "memory");                     \
        __builtin_amdgcn_sched_barrier(0);                                     \
        f16x8 ha0 = __builtin_shufflevector(t0, t1, 0, 1, 2, 3, 4, 5, 6, 7);   \
        f16x8 ha1 = __builtin_shufflevector(t2, t3, 0, 1, 2, 3, 4, 5, 6, 7);   \
        _Pragma("unroll")                                                      \
        for (int g = 0; g < 4; ++g)                                            \
            _Pragma("unroll")                                                  \
            for (int q = 0; q < 2; ++q) {                                      \
                zacc[g][q] = MFMA(ha0, whf[g][q][0], zacc[g][q], 0, 0, 0);     \
                zacc[g][q] = MFMA(ha1, whf[g][q][1], zacc[g][q], 0, 0, 0);     \
            }                                                                  \
        _Pragma("unroll")                                                      \
        for (int q = 0; q < 2; ++q) {                                          \
            f32x4 zi = zacc[0][q], zf = zacc[1][q],                            \
                  zg = zacc[2][q], zo = zacc[3][q];                            \
            f16x4 ph;                                                          \
            GATEC(q, 0) GATEC(q, 1) GATEC(q, 2) GATEC(q, 3)                    \
            *reinterpret_cast<f16x4*>(                                         \
                &h_lds[P ^ 1][W * 32 + q * 16 + cc][kg * 4]) = ph;             \
            if (DO_XNEXT) {                                                    \
                _Pragma("unroll")                                              \
                for (int g = 0; g < 4; ++g) {                                  \
                    f32x4 a = {bgv[g][q], bgv[g][q], bgv[g][q], bgv[g][q]};    \
                    a = MFMA(xa0, wxf[g][q][0], a, 0, 0, 0);                   \
                    zacc[g][q] = MFMA(xa1, wxf[g][q][1], a, 0, 0, 0);          \
                }                                                              \
            }                                                                  \
        }                                                                      \
        if (DO_LOAD) {                                                         \
            xp0 = *(const f32x4*)(xld + 0);                                    \
            xp1 = *(const f32x4*)(xld + 4);                                    \
            xp2 = *(const f32x4*)(xld + 32);                                   \
            xp3 = *(const f32x4*)(xld + 36);                                   \
            xld += F_N;                                                        \
        }                                                                      \
        BAR();                                                                 \
    }

    for (int it = 0; it < 83; ++it) {   // t = 0..165
        STEP(0, 1, 1)
        STEP(1, 1, 1)
    }
    STEP(0, 0, 1)   // t=166: uses x(167), no further load
    STEP(1, 0, 0)   // t=167: final h(168) -> h_lds[0]
#undef STEP
#undef GATEC

    // ---- MLP head: relu(h@W1 + b1)@W2 + b2 + x[:, -1, 0] ------------------
    {
        const int r1 = tid & 15;
        const int u1 = tid >> 4;        // 0..7
        float hrow[H_N];
        #pragma unroll
        for (int hk = 0; hk < H_N; ++hk) hrow[hk] = (float)h_lds[0][hk][r1];
        for (int uu = u1; uu < HEAD_N; uu += 8) {
            float s = b1[uu];
            #pragma unroll
            for (int hk = 0; hk < H_N; ++hk)
                s = fmaf(hrow[hk], W1[hk * HEAD_N + uu], s);
            hrelu[r1][uu] = fmaxf(s, 0.0f);
        }
    }
    __syncthreads();
    {
        const int r2 = tid >> 3;        // 0..15
        const int p  = tid & 7;
        float s = 0.0f;
        for (int uu = p; uu < HEAD_N; uu += 8) s += hrelu[r2][uu] * W2[uu];
        #pragma unroll
        for (int off = 4; off > 0; off >>= 1) s += __shfl_xor(s, off, 8);
        if (p == 0) {
            float res = x[(size_t)(R0 + r2) * RS + (T_N - 1) * F_N + 0];
            out[R0 + r2] = s + b2[0] + res;
        }
    }
}

extern "C" void kernel_launch(void* const* d_in, const int* in_sizes, int n_in,
                              void* d_out, int out_size, void* d_ws, size_t ws_size,
                              hipStream_t stream) {
    const float* x  = (const float*)d_in[0];
    const float* Wx = (const float*)d_in[1];
    const float* Wh = (const float*)d_in[2];
    const float* b  = (const float*)d_in[3];
    const float* W1 = (const float*)d_in[4];
    const float* b1 = (const float*)d_in[5];
    const float* W2 = (const float*)d_in[6];
    const float* b2 = (const float*)d_in[7];
    float* out = (float*)d_out;

    lstm_fused<<<dim3(B_N / 16), dim3(128), 0, stream>>>(x, Wx, Wh, b, W1, b1, W2, b2, out);
}

// Round 14
// 194.645 us; speedup vs baseline: 2.3133x; 1.3742x over previous
//
#include <hip/hip_runtime.h>

// LSTM (B=8192, T=168, F=64, H=50) + MLP head, fused, f16 MFMA + fp32 state.
// Round 14: 4-wave blocks (2 waves/SIMD). Each 256-thr block owns one 16-row
// chain; wave W owns units [W*16, W*16+16) = 4 col-tiles (64 weight VGPRs).
// Per step/wave: 4x ds_read_b64_tr_b16 (r12/r13-validated addressing, full
// 64-unit h), 8 h-MFMA + 8 x-MFMA, 4 cells merged-rcp exp2 gates, 1 f16x4
// h-write, ONE 4-wave lgkm barrier. x global->reg A-frag with 2-step-deep
// ping-pong prefetch (r13's ~600cy vmcnt stall fixed). 512 blocks.

#define B_N 8192
#define T_N 168
#define F_N 64
#define H_N 50
#define HEAD_N 100
#define RS (T_N * F_N)  // 10752

typedef _Float16 f16x8 __attribute__((ext_vector_type(8)));
typedef _Float16 f16x4 __attribute__((ext_vector_type(4)));
typedef float    f32x4 __attribute__((ext_vector_type(4)));

#define LOG2E  1.4426950408889634f
#define LOG2E2 2.8853900817779268f
#define MFMA __builtin_amdgcn_mfma_f32_16x16x32_f16

// LDS barrier: drain own LDS ops, barrier, compiler fence both sides.
// vmcnt NOT drained: x prefetch stays in flight across steps.
#define BAR()                                                        \
    do {                                                             \
        asm volatile("s_waitcnt lgkmcnt(0)" ::: "memory");           \
        __builtin_amdgcn_s_barrier();                                \
        asm volatile("" ::: "memory");                               \
    } while (0)

__device__ __forceinline__ float rcp_f(float v) { return __builtin_amdgcn_rcpf(v); }
#if __has_builtin(__builtin_amdgcn_exp2f)
__device__ __forceinline__ float exp2_f(float v) { return __builtin_amdgcn_exp2f(v); }
#else
__device__ __forceinline__ float exp2_f(float v) { return __expf(0.6931471805599453f * v); }
#endif

__device__ __forceinline__ f16x8 cvt8(f32x4 a, f32x4 b) {
    f16x8 r;
    #pragma unroll
    for (int j = 0; j < 4; ++j) { r[j] = (_Float16)a[j]; r[4 + j] = (_Float16)b[j]; }
    return r;
}

__launch_bounds__(256, 2)
__global__ void lstm_fused(const float* __restrict__ x,
                           const float* __restrict__ Wx,
                           const float* __restrict__ Wh,
                           const float* __restrict__ b,
                           const float* __restrict__ W1,
                           const float* __restrict__ b1,
                           const float* __restrict__ W2,
                           const float* __restrict__ b2,
                           float* __restrict__ out)
{
    // h buffer [unit][row] f16, double-buffered, 128B-aligned (tr windows).
    __shared__ alignas(128) _Float16 h_lds[2][64][16];
    __shared__ float hrelu[16][HEAD_N];

    const int tid  = threadIdx.x;      // 0..255
    const int lane = tid & 63;
    const int W    = tid >> 6;         // wave id 0..3: units W*16..+16
    const int cc   = lane & 15;        // batch row / unit col
    const int kg   = lane >> 4;        // k-group
    const int R0   = blockIdx.x * 16;  // batch rows of this block

    // ---- this wave's 4 col-tiles of weights, VGPR-resident, prescaled -----
    // tile g: gate g, unit u = W*16 + cc
    f16x8 wxf[4][2], whf[4][2];
    float bgv[4];
    const int  u  = W * 16 + cc;
    const bool uv = (u < H_N);
    #pragma unroll
    for (int g = 0; g < 4; ++g) {
        const float sc = (g == 2) ? LOG2E2 : LOG2E;   // g-gate: fold tanh's 2x
        bgv[g] = uv ? b[g * H_N + u] * sc : 0.0f;
        #pragma unroll
        for (int ks = 0; ks < 2; ++ks) {
            f16x8 vx, vh;
            #pragma unroll
            for (int i = 0; i < 8; ++i) {
                int k = ks * 32 + kg * 8 + i;   // same k-map as A-frags
                vx[i] = (_Float16)(uv ? Wx[k * 200 + g * H_N + u] * sc : 0.0f);
                vh[i] = (_Float16)((uv && k < H_N) ? Wh[k * 200 + g * H_N + u] * sc : 0.0f);
            }
            wxf[g][ks] = vx;
            whf[g][ks] = vh;
        }
    }

    // zero h(0) buffer 0 (2048 B = 256 f16x4 chunks, one per thread)
    reinterpret_cast<f16x4*>(&h_lds[0][0][0])[tid] = (f16x4){0, 0, 0, 0};

    // x A-frag loads: lane reads row R0+cc, k-cols kg*8 + {0..7, 32..39}
    const float* xb = x + (size_t)(R0 + cc) * RS + kg * 8;
    f32x4 xp0_0, xp0_1, xp0_2, xp0_3;   // even-step set: x(t+1), t even
    f32x4 xp1_0, xp1_1, xp1_2, xp1_3;   // odd-step set
    f32x4 zacc[4];                      // z accumulators [gate]
    float cst[4];                       // cell state (4 rows of unit u)
    #pragma unroll
    for (int i = 0; i < 4; ++i) cst[i] = 0.0f;

    {   // prologue: zacc = bias + x(0)@Wx ; xp0 = x(1), xp1 = x(2)
        f32x4 t0 = *(const f32x4*)(xb + 0);
        f32x4 t1 = *(const f32x4*)(xb + 4);
        f32x4 t2 = *(const f32x4*)(xb + 32);
        f32x4 t3 = *(const f32x4*)(xb + 36);
        xp0_0 = *(const f32x4*)(xb + F_N + 0);
        xp0_1 = *(const f32x4*)(xb + F_N + 4);
        xp0_2 = *(const f32x4*)(xb + F_N + 32);
        xp0_3 = *(const f32x4*)(xb + F_N + 36);
        xp1_0 = *(const f32x4*)(xb + 2 * F_N + 0);
        xp1_1 = *(const f32x4*)(xb + 2 * F_N + 4);
        xp1_2 = *(const f32x4*)(xb + 2 * F_N + 32);
        xp1_3 = *(const f32x4*)(xb + 2 * F_N + 36);
        f16x8 xa0 = cvt8(t0, t1), xa1 = cvt8(t2, t3);
        #pragma unroll
        for (int g = 0; g < 4; ++g) {
            f32x4 a = {bgv[g], bgv[g], bgv[g], bgv[g]};
            a = MFMA(xa0, wxf[g][0], a, 0, 0, 0);
            zacc[g] = MFMA(xa1, wxf[g][1], a, 0, 0, 0);
        }
    }
    const float* xld = xb + 3 * F_N;   // next load: x(3) (2-step-deep)
    __syncthreads();                   // h(0) visible

    // tr-read base (r12-validated): window = base + kg*256, lane slot cc*8.
    // offsets {0,128,1024,1152} -> units {kg*8..+3, +4..+7, 32+kg*8..+3, ..+7}
    const uint32_t trbase0 =
        (uint32_t)(uintptr_t)(&h_lds[0][0][0]) + (kg << 8) + (cc << 3);
    const uint32_t trbase1 = trbase0 + 2048;

    // gates: merged-rcp pairs, exp2 domain (weights prescaled; g by 2x)
#define GATEC(i)                                                               \
    {                                                                          \
        float A_ = exp2_f(-zi[i]);                                             \
        float Bv = exp2_f(-zg[i]);                                             \
        float Fv = exp2_f(-zf[i]);                                             \
        float sf_ = rcp_f(1.0f + Fv);                                          \
        float r1_ = rcp_f((1.0f + A_) * (1.0f + Bv));                          \
        float cn_ = fmaf(sf_, cst[i], (1.0f - Bv) * r1_);                      \
        cst[i] = cn_;                                                          \
        float Cv = exp2_f(-zo[i]);                                             \
        float eD_ = fminf(-LOG2E2 * cn_, 80.0f);                               \
        float Dv = exp2_f(eD_);                                                \
        float r2_ = rcp_f((1.0f + Cv) * (1.0f + Dv));                          \
        ph[i] = (_Float16)((1.0f - Dv) * r2_);                                 \
    }

    // Step t (P=t&1): tr-read h(t) from h_lds[P] (xa cvt in latency shadow);
    // z += h@Wh; gates -> h(t+1) write (this wave's 16 units); zacc reinit =
    // bias + x(t+1)@Wx; load x(t+3) into set P; ONE 4-wave barrier.
#define STEP(P, DO_LOAD, DO_XNEXT)                                             \
    {                                                                          \
        f16x4 t0, t1, t2, t3;                                                  \
        asm volatile("ds_read_b64_tr_b16 %0, %1"                               \
                     : "=v"(t0) : "v"(trbase##P) : "memory");                  \
        asm volatile("ds_read_b64_tr_b16 %0, %1 offset:128"                    \
                     : "=v"(t1) : "v"(trbase##P) : "memory");                  \
        asm volatile("ds_read_b64_tr_b16 %0, %1 offset:1024"                   \
                     : "=v"(t2) : "v"(trbase##P) : "memory");                  \
        asm volatile("ds_read_b64_tr_b16 %0, %1 offset:1152"                   \
                     : "=v"(t3) : "v"(trbase##P) : "memory");                  \
        f16x8 xa0, xa1;                                                        \
        if (DO_XNEXT) {                                                        \
            xa0 = cvt8(xp##P##_0, xp##P##_1);                                  \
            xa1 = cvt8(xp##P##_2, xp##P##_3);                                  \
        }                                                                      \
        asm volatile("s_waitcnt lgkmcnt(0)" ::: "memory");                     \
        __builtin_amdgcn_sched_barrier(0);                                     \
        f16x8 ha0 = __builtin_shufflevector(t0, t1, 0, 1, 2, 3, 4, 5, 6, 7);   \
        f16x8 ha1 = __builtin_shufflevector(t2, t3, 0, 1, 2, 3, 4, 5, 6, 7);   \
        _Pragma("unroll")                                                      \
        for (int g = 0; g < 4; ++g) {                                          \
            zacc[g] = MFMA(ha0, whf[g][0], zacc[g], 0, 0, 0);                  \
            zacc[g] = MFMA(ha1, whf[g][1], zacc[g], 0, 0, 0);                  \
        }                                                                      \
        {                                                                      \
            f32x4 zi = zacc[0], zf = zacc[1], zg = zacc[2], zo = zacc[3];      \
            f16x4 ph;                                                          \
            GATEC(0) GATEC(1) GATEC(2) GATEC(3)                                \
            *reinterpret_cast<f16x4*>(&h_lds[P ^ 1][W * 16 + cc][kg * 4]) = ph;\
            if (DO_XNEXT) {                                                    \
                _Pragma("unroll")                                              \
                for (int g = 0; g < 4; ++g) {                                  \
                    f32x4 a = {bgv[g], bgv[g], bgv[g], bgv[g]};                \
                    a = MFMA(xa0, wxf[g][0], a, 0, 0, 0);                      \
                    zacc[g] = MFMA(xa1, wxf[g][1], a, 0, 0, 0);                \
                }                                                              \
            }                                                                  \
        }                                                                      \
        if (DO_LOAD) {                                                         \
            xp##P##_0 = *(const f32x4*)(xld + 0);                              \
            xp##P##_1 = *(const f32x4*)(xld + 4);                              \
            xp##P##_2 = *(const f32x4*)(xld + 32);                             \
            xp##P##_3 = *(const f32x4*)(xld + 36);                             \
            xld += F_N;                                                        \
        }                                                                      \
        BAR();                                                                 \
    }

    for (int it = 0; it < 82; ++it) {   // t = 0..163 (loads x(3)..x(166))
        STEP(0, 1, 1)
        STEP(1, 1, 1)
    }
    STEP(0, 1, 1)   // t=164: uses x(165), loads x(167)
    STEP(1, 0, 1)   // t=165: uses x(166)
    STEP(0, 0, 1)   // t=166: uses x(167)
    STEP(1, 0, 0)   // t=167: final h(168) -> h_lds[0]
#undef STEP
#undef GATEC

    // ---- MLP head: relu(h@W1 + b1)@W2 + b2 + x[:, -1, 0] ------------------
    // (last BAR drained all h writes; h(168) in h_lds[0], [unit][row])
    {
        const int r1 = tid & 15;
        const int u1 = tid >> 4;        // 0..15
        float hrow[H_N];
        #pragma unroll
        for (int hk = 0; hk < H_N; ++hk) hrow[hk] = (float)h_lds[0][hk][r1];
        for (int uu = u1; uu < HEAD_N; uu += 16) {
            float s = b1[uu];
            #pragma unroll
            for (int hk = 0; hk < H_N; ++hk)
                s = fmaf(hrow[hk], W1[hk * HEAD_N + uu], s);
            hrelu[r1][uu] = fmaxf(s, 0.0f);
        }
    }
    __syncthreads();
    {
        const int r2 = tid >> 4;        // 0..15
        const int p  = tid & 15;
        float s = 0.0f;
        for (int uu = p; uu < HEAD_N; uu += 16) s += hrelu[r2][uu] * W2[uu];
        #pragma unroll
        for (int off = 8; off > 0; off >>= 1) s += __shfl_xor(s, off, 16);
        if (p == 0) {
            float res = x[(size_t)(R0 + r2) * RS + (T_N - 1) * F_N + 0];
            out[R0 + r2] = s + b2[0] + res;
        }
    }
}

extern "C" void kernel_launch(void* const* d_in, const int* in_sizes, int n_in,
                              void* d_out, int out_size, void* d_ws, size_t ws_size,
                              hipStream_t stream) {
    const float* x  = (const float*)d_in[0];
    const float* Wx = (const float*)d_in[1];
    const float* Wh = (const float*)d_in[2];
    const float* b  = (const float*)d_in[3];
    const float* W1 = (const float*)d_in[4];
    const float* b1 = (const float*)d_in[5];
    const float* W2 = (const float*)d_in[6];
    const float* b2 = (const float*)d_in[7];
    float* out = (float*)d_out;

    lstm_fused<<<dim3(B_N / 16), dim3(256), 0, stream>>>(x, Wx, Wh, b, W1, b1, W2, b2, out);
}

// Round 15
// 150.809 us; speedup vs baseline: 2.9858x; 1.2907x over previous
//
#include <hip/hip_runtime.h>

// LSTM (B=8192, T=168, F=64, H=50) + MLP head, fused, f16 MFMA + fp32 state.
// Round 15: r7 champion structure (producer/consumer wave split, merged-rcp
// exp2 gates, 1 lgkm-barrier/step, setprio on h-waves) + the one validated
// improvement from r12-r14: h stored [unit][row] with f16x4 coalesced writes
// and ds_read_b64_tr_b16 hardware-transpose reads (addressing validated 3x)
// replacing 4x scattered ds_write_b16 + 2x ds_read_b128 on the h-critical
// path. 512 blocks x 512 threads (waves 0-3 x-role, 4-7 h-role), 2 blk/CU.

#define B_N 8192
#define T_N 168
#define F_N 64
#define H_N 50
#define HEAD_N 100
#define ROWSTRIDE (T_N * F_N)  // 10752

typedef _Float16 f16x8 __attribute__((ext_vector_type(8)));
typedef _Float16 f16x4 __attribute__((ext_vector_type(4)));
typedef float    f32x4 __attribute__((ext_vector_type(4)));

#define LOG2E  1.4426950408889634f
#define LOG2E2 2.8853900817779268f

#define MFMA __builtin_amdgcn_mfma_f32_16x16x32_f16

// LDS-only barrier: drain own LDS ops, barrier, compiler fence both sides.
// vmcnt NOT drained: register-destined global prefetch stays in flight.
#define BAR()                                                        \
    do {                                                             \
        asm volatile("s_waitcnt lgkmcnt(0)" ::: "memory");           \
        __builtin_amdgcn_s_barrier();                                \
        asm volatile("" ::: "memory");                               \
    } while (0)

__device__ __forceinline__ float rcp_f(float v) { return __builtin_amdgcn_rcpf(v); }
#if __has_builtin(__builtin_amdgcn_exp2f)
__device__ __forceinline__ float exp2_f(float v) { return __builtin_amdgcn_exp2f(v); }
#else
__device__ __forceinline__ float exp2_f(float v) { return __expf(0.6931471805599453f * v); }
#endif

__launch_bounds__(512, 4)
__global__ void lstm_fused(const float* __restrict__ x,
                           const float* __restrict__ Wx,
                           const float* __restrict__ Wh,
                           const float* __restrict__ b,
                           const float* __restrict__ W1,
                           const float* __restrict__ b1,
                           const float* __restrict__ W2,
                           const float* __restrict__ b2,
                           float* __restrict__ out)
{
    __shared__ alignas(16) _Float16 xb[2][16][72];        // xb[t&1] = x(t)
    __shared__ alignas(128) _Float16 h_lds[2][64][16];    // [unit][row], dbuf
    __shared__ alignas(16) float axb[2][4][4][64][4];     // [P][tile][gate][lane][4]
    __shared__ float hrelu[16][HEAD_N];

    const int tid  = threadIdx.x;
    const int lane = tid & 63;
    const int w    = tid >> 6;         // 0..7; 0-3 x-waves, 4-7 h-waves
    const int ut   = w & 3;            // unit-tile (16 units each)
    const int rowA = lane & 15;        // A-frag row == C-frag col
    const int kg   = lane >> 4;        // k-group 0..3
    const int R0   = blockIdx.x * 16;  // batch rows of this block
    const int jl   = ut * 16 + rowA;   // unit index 0..63
    const bool jv  = (jl < H_N);

    // ---- role-specific weight fragments (VGPR-resident, exp2-prescaled) --
    f16x8 wxf[4][2], whf[4][2];
    float bg[4];
    if (w < 4) {
        #pragma unroll
        for (int g = 0; g < 4; ++g) {
            const float sc = (g == 2) ? LOG2E2 : LOG2E;
            bg[g] = jv ? b[g * H_N + jl] * sc : 0.0f;
            #pragma unroll
            for (int ks = 0; ks < 2; ++ks) {
                f16x8 v;
                #pragma unroll
                for (int i = 0; i < 8; ++i) {
                    int k = ks * 32 + kg * 8 + i;     // same k-map as A-frags
                    v[i] = (_Float16)(jv ? Wx[k * 200 + g * H_N + jl] * sc : 0.0f);
                }
                wxf[g][ks] = v;
            }
        }
    } else {
        #pragma unroll
        for (int g = 0; g < 4; ++g) {
            const float sc = (g == 2) ? LOG2E2 : LOG2E;
            #pragma unroll
            for (int ks = 0; ks < 2; ++ks) {
                f16x8 v;
                #pragma unroll
                for (int i = 0; i < 8; ++i) {
                    int k = ks * 32 + kg * 8 + i;
                    v[i] = (_Float16)((jv && k < H_N) ? Wh[k * 200 + g * H_N + jl] * sc : 0.0f);
                }
                whf[g][ks] = v;
            }
        }
    }

    float c0 = 0.f, c1 = 0.f, c2 = 0.f, c3 = 0.f;   // h-wave fp32 cell state

    // zero h(0) buffer 0 ([unit][row] = 1024 f16)
    for (int idx = tid; idx < 1024; idx += 512)
        ((_Float16*)h_lds[0])[idx] = (_Float16)0.0f;

    // x staging map (x-waves = tid 0..255): (row tid>>4, 4 floats), coalesced
    const int xr  = (tid >> 4) & 15;
    const int xf0 = (tid & 15) * 4;
    const float* xrow = x + (size_t)(R0 + xr) * ROWSTRIDE + xf0;
    f32x4 xpr0, xpr1;     // in-flight x rows: xpr[t&1] LDS-written at step t
    if (w < 4) {
        f32x4 v0 = *reinterpret_cast<const f32x4*>(xrow);
        f32x4 v1 = *reinterpret_cast<const f32x4*>(xrow + F_N);
        xpr0 = *reinterpret_cast<const f32x4*>(xrow + 2 * F_N);   // x(2)
        xpr1 = *reinterpret_cast<const f32x4*>(xrow + 3 * F_N);   // x(3)
        f16x4 a, c4;
        #pragma unroll
        for (int j = 0; j < 4; ++j) { a[j] = (_Float16)v0[j]; c4[j] = (_Float16)v1[j]; }
        *reinterpret_cast<f16x4*>(&xb[0][xr][xf0]) = a;   // x(0)
        *reinterpret_cast<f16x4*>(&xb[1][xr][xf0]) = c4;  // x(1)
    }
    const float* xld = xrow + 4 * F_N;   // next global load: x(4)
    __syncthreads();

    if (w < 4) {   // prologue: ax(0) = b + x(0)@Wx -> axb[0]
        f16x8 xa0 = *reinterpret_cast<const f16x8*>(&xb[0][rowA][kg * 8]);
        f16x8 xa1 = *reinterpret_cast<const f16x8*>(&xb[0][rowA][32 + kg * 8]);
        f32x4 a0 = {bg[0], bg[0], bg[0], bg[0]};
        f32x4 a1 = {bg[1], bg[1], bg[1], bg[1]};
        f32x4 a2 = {bg[2], bg[2], bg[2], bg[2]};
        f32x4 a3 = {bg[3], bg[3], bg[3], bg[3]};
        a0 = MFMA(xa0, wxf[0][0], a0, 0, 0, 0);
        a1 = MFMA(xa0, wxf[1][0], a1, 0, 0, 0);
        a2 = MFMA(xa0, wxf[2][0], a2, 0, 0, 0);
        a3 = MFMA(xa0, wxf[3][0], a3, 0, 0, 0);
        a0 = MFMA(xa1, wxf[0][1], a0, 0, 0, 0);
        a1 = MFMA(xa1, wxf[1][1], a1, 0, 0, 0);
        a2 = MFMA(xa1, wxf[2][1], a2, 0, 0, 0);
        a3 = MFMA(xa1, wxf[3][1], a3, 0, 0, 0);
        *reinterpret_cast<f32x4*>(&axb[0][ut][0][lane][0]) = a0;
        *reinterpret_cast<f32x4*>(&axb[0][ut][1][lane][0]) = a1;
        *reinterpret_cast<f32x4*>(&axb[0][ut][2][lane][0]) = a2;
        *reinterpret_cast<f32x4*>(&axb[0][ut][3][lane][0]) = a3;
    }
    __syncthreads();

    // tr-read base (validated r12/r13/r14): window = base + kg*256, lane slot
    // rowA*8; offsets {0,128,1024,1152} -> A-frag k = units {kg*8..+3, +4..+7,
    // 32+kg*8..+3, 32+kg*8+4..+7} for row = rowA. Buffers 2048 B apart.
    const uint32_t trbase0 =
        (uint32_t)(uintptr_t)(&h_lds[0][0][0]) + (kg << 8) + (rowA << 3);
    const uint32_t trbase1 = trbase0 + 2048;

    // gates v2: merged-rcp pairs, exp2 domain (weights prescaled; g by 2x).
#define GATE1(ii, cvar)                                                        \
    {                                                                          \
        float A_ = exp2_f(-zi[ii]);                                            \
        float B_ = exp2_f(-zg[ii]);                                            \
        float F_ = exp2_f(-zf[ii]);                                            \
        float sf_ = rcp_f(1.0f + F_);                                          \
        float r1_ = rcp_f((1.0f + A_) * (1.0f + B_));                          \
        float cn_ = fmaf(sf_, cvar, (1.0f - B_) * r1_);                        \
        cvar = cn_;                                                            \
        float C_ = exp2_f(-zo[ii]);                                            \
        float eD_ = fminf(-LOG2E2 * cn_, 80.0f);                               \
        float D_ = exp2_f(eD_);                                                \
        float r2_ = rcp_f((1.0f + C_) * (1.0f + D_));                          \
        ph[ii] = (_Float16)((1.0f - D_) * r2_);                                \
    }

#define XSTEP(P, DO_XW, DO_LOAD)                                               \
    {                                                                          \
        f16x8 xa0 = *reinterpret_cast<const f16x8*>(&xb[P ^ 1][rowA][kg * 8]);      \
        f16x8 xa1 = *reinterpret_cast<const f16x8*>(&xb[P ^ 1][rowA][32 + kg * 8]); \
        f32x4 a0 = {bg[0], bg[0], bg[0], bg[0]};                               \
        f32x4 a1 = {bg[1], bg[1], bg[1], bg[1]};                               \
        f32x4 a2 = {bg[2], bg[2], bg[2], bg[2]};                               \
        f32x4 a3 = {bg[3], bg[3], bg[3], bg[3]};                               \
        a0 = MFMA(xa0, wxf[0][0], a0, 0, 0, 0);                                \
        a1 = MFMA(xa0, wxf[1][0], a1, 0, 0, 0);                                \
        a2 = MFMA(xa0, wxf[2][0], a2, 0, 0, 0);                                \
        a3 = MFMA(xa0, wxf[3][0], a3, 0, 0, 0);                                \
        a0 = MFMA(xa1, wxf[0][1], a0, 0, 0, 0);                                \
        a1 = MFMA(xa1, wxf[1][1], a1, 0, 0, 0);                                \
        a2 = MFMA(xa1, wxf[2][1], a2, 0, 0, 0);                                \
        a3 = MFMA(xa1, wxf[3][1], a3, 0, 0, 0);                                \
        *reinterpret_cast<f32x4*>(&axb[P ^ 1][ut][0][lane][0]) = a0;           \
        *reinterpret_cast<f32x4*>(&axb[P ^ 1][ut][1][lane][0]) = a1;           \
        *reinterpret_cast<f32x4*>(&axb[P ^ 1][ut][2][lane][0]) = a2;           \
        *reinterpret_cast<f32x4*>(&axb[P ^ 1][ut][3][lane][0]) = a3;           \
        if (DO_XW) {                                                           \
            f16x4 xc;                                                          \
            xc[0] = (_Float16)xpr##P[0]; xc[1] = (_Float16)xpr##P[1];          \
            xc[2] = (_Float16)xpr##P[2]; xc[3] = (_Float16)xpr##P[3];          \
            *reinterpret_cast<f16x4*>(&xb[P][xr][xf0]) = xc;                   \
        }                                                                      \
        if (DO_LOAD) { xpr##P = *reinterpret_cast<const f32x4*>(xld); xld += F_N; } \
        BAR();                                                                 \
    }

    // h-wave step t (P=t&1): tr-read h(t); z = axb[P] + h(t)@Wh; gates;
    // h(t+1) -> h_lds[P^1][unit jl][rows kg*4..+4] as one f16x4 write.
#define HSTEP(P)                                                               \
    {                                                                          \
        __builtin_amdgcn_s_setprio(1);                                         \
        f16x4 t0, t1, t2, t3;                                                  \
        asm volatile("ds_read_b64_tr_b16 %0, %1"                               \
                     : "=v"(t0) : "v"(trbase##P) : "memory");                  \
        asm volatile("ds_read_b64_tr_b16 %0, %1 offset:128"                    \
                     : "=v"(t1) : "v"(trbase##P) : "memory");                  \
        asm volatile("ds_read_b64_tr_b16 %0, %1 offset:1024"                   \
                     : "=v"(t2) : "v"(trbase##P) : "memory");                  \
        asm volatile("ds_read_b64_tr_b16 %0, %1 offset:1152"                   \
                     : "=v"(t3) : "v"(trbase##P) : "memory");                  \
        f32x4 zi = *reinterpret_cast<const f32x4*>(&axb[P][ut][0][lane][0]);   \
        f32x4 zf = *reinterpret_cast<const f32x4*>(&axb[P][ut][1][lane][0]);   \
        f32x4 zg = *reinterpret_cast<const f32x4*>(&axb[P][ut][2][lane][0]);   \
        f32x4 zo = *reinterpret_cast<const f32x4*>(&axb[P][ut][3][lane][0]);   \
        asm volatile("s_waitcnt lgkmcnt(0)" ::: "memory");                     \
        __builtin_amdgcn_sched_barrier(0);                                     \
        f16x8 ha0 = __builtin_shufflevector(t0, t1, 0, 1, 2, 3, 4, 5, 6, 7);   \
        f16x8 ha1 = __builtin_shufflevector(t2, t3, 0, 1, 2, 3, 4, 5, 6, 7);   \
        zi = MFMA(ha0, whf[0][0], zi, 0, 0, 0);                                \
        zf = MFMA(ha0, whf[1][0], zf, 0, 0, 0);                                \
        zg = MFMA(ha0, whf[2][0], zg, 0, 0, 0);                                \
        zo = MFMA(ha0, whf[3][0], zo, 0, 0, 0);                                \
        zi = MFMA(ha1, whf[0][1], zi, 0, 0, 0);                                \
        zf = MFMA(ha1, whf[1][1], zf, 0, 0, 0);                                \
        zg = MFMA(ha1, whf[2][1], zg, 0, 0, 0);                                \
        zo = MFMA(ha1, whf[3][1], zo, 0, 0, 0);                                \
        f16x4 ph;                                                              \
        GATE1(0, c0)                                                           \
        GATE1(1, c1)                                                           \
        GATE1(2, c2)                                                           \
        GATE1(3, c3)                                                           \
        *reinterpret_cast<f16x4*>(&h_lds[P ^ 1][jl][kg * 4]) = ph;             \
        __builtin_amdgcn_s_setprio(0);                                         \
        BAR();                                                                 \
    }

    // Both role-loops execute EXACTLY 168 barriers (mirror structure).
    if (w < 4) {
        for (int it = 0; it < 82; ++it) {   // t = 0..163
            XSTEP(0, 1, 1)
            XSTEP(1, 1, 1)
        }
        XSTEP(0, 1, 0)   // t=164: ax(165), write x(166)
        XSTEP(1, 1, 0)   // t=165: ax(166), write x(167)
        XSTEP(0, 0, 0)   // t=166: ax(167)
        BAR();           // t=167: x-waves just sync
    } else {
        for (int it = 0; it < 82; ++it) {   // t = 0..163
            HSTEP(0)
            HSTEP(1)
        }
        HSTEP(0)   // t=164
        HSTEP(1)   // t=165
        HSTEP(0)   // t=166
        HSTEP(1)   // t=167: final h(168) -> h_lds[0]
    }
#undef XSTEP
#undef HSTEP
#undef GATE1

    // ---- MLP head: relu(h@W1 + b1)@W2 + b2 + x[:, -1, 0] ------------------
    // h(168) in h_lds[0], [unit][row] layout.
    if (tid < 256) {
        const int r1 = tid & 15;
        const int u1 = tid >> 4;
        float hrow[H_N];
        #pragma unroll
        for (int hk = 0; hk < H_N; ++hk) hrow[hk] = (float)h_lds[0][hk][r1];
        for (int uu = u1; uu < HEAD_N; uu += 16) {
            float s = b1[uu];
            #pragma unroll
            for (int hk = 0; hk < H_N; ++hk) s += hrow[hk] * W1[hk * HEAD_N + uu];
            hrelu[r1][uu] = fmaxf(s, 0.0f);
        }
    }
    __syncthreads();
    if (tid < 256) {
        const int r2 = tid >> 4;
        const int p  = tid & 15;
        float s = 0.0f;
        for (int uu = p; uu < HEAD_N; uu += 16) s += hrelu[r2][uu] * W2[uu];
        #pragma unroll
        for (int off = 8; off > 0; off >>= 1) s += __shfl_xor(s, off, 16);
        if (p == 0) {
            float res = x[(size_t)(R0 + r2) * ROWSTRIDE + (T_N - 1) * F_N + 0];
            out[R0 + r2] = s + b2[0] + res;
        }
    }
}

extern "C" void kernel_launch(void* const* d_in, const int* in_sizes, int n_in,
                              void* d_out, int out_size, void* d_ws, size_t ws_size,
                              hipStream_t stream) {
    const float* x  = (const float*)d_in[0];
    const float* Wx = (const float*)d_in[1];
    const float* Wh = (const float*)d_in[2];
    const float* b  = (const float*)d_in[3];
    const float* W1 = (const float*)d_in[4];
    const float* b1 = (const float*)d_in[5];
    const float* W2 = (const float*)d_in[6];
    const float* b2 = (const float*)d_in[7];
    float* out = (float*)d_out;

    lstm_fused<<<dim3(B_N / 16), dim3(512), 0, stream>>>(x, Wx, Wh, b, W1, b1, W2, b2, out);
}